// Round 5
// baseline (521.586 us; speedup 1.0000x reference)
//
#include <hip/hip_runtime.h>
#include <math.h>

#define LL 2
#define BB 32
#define SS 2048
#define HH 512
#define DD 1024      // 2*H
#define W4S 2048     // attn_w row stride = 4*H

// k_scores tiling
#define BM 64
#define BN 256
#define BK 64
#define NT (DD / BK)     // 16 k-tiles

typedef __attribute__((ext_vector_type(8))) short bf16x8;
typedef __attribute__((ext_vector_type(4))) float f32x4;

// fp32 pair -> packed bf16x2, round-to-nearest-even (one-time pack)
__device__ inline unsigned pk2_rne(float a, float b) {
    unsigned ua = __float_as_uint(a), ub = __float_as_uint(b);
    unsigned ra = (ua + 0x7fffu + ((ua >> 16) & 1u)) >> 16;
    unsigned rb = (ub + 0x7fffu + ((ub >> 16) & 1u)) & 0xffff0000u;
    return ra | rb;
}

// fp32 pair -> packed bf16x2, round-half-up: 2 adds + v_perm
__device__ inline unsigned pk2_hu(float a, float b) {
    unsigned ua = __float_as_uint(a) + 0x8000u;
    unsigned ub = __float_as_uint(b) + 0x8000u;
    return __builtin_amdgcn_perm(ub, ua, 0x07060302u);
}

__device__ inline float fast_tanh(float x) {
    x = fminf(9.f, fmaxf(-9.f, x));
    float e = __expf(2.f * x);
    return 1.f - 2.f * __builtin_amdgcn_rcpf(e + 1.f);
}

// async global->LDS, 16 B per lane; LDS dest = base + lane*16 (HW rule)
__device__ inline void gl_lds16(const unsigned short* g, short* l) {
    __builtin_amdgcn_global_load_lds(
        (const __attribute__((address_space(1))) unsigned int*)g,
        (__attribute__((address_space(3))) unsigned int*)l, 16, 0, 0);
}

// ---------------- fused prep: zero scores | pack w_e | base ------------------
__global__ __launch_bounds__(256) void k_prep(const float* __restrict__ hidden,
                                              const float* __restrict__ attn_w,
                                              const float* __restrict__ attn_b,
                                              unsigned short* __restrict__ Bp,
                                              float* __restrict__ base,
                                              float* __restrict__ scores) {
    int bx = blockIdx.x;
    if (bx < BB * SS / 256) {                       // zero scores
        scores[bx * 256 + threadIdx.x] = 0.f;
        return;
    }
    bx -= BB * SS / 256;
    if (bx < HH) {                                  // pack w_e row bx -> bf16
        int t = threadIdx.x;
        float4 v = *(const float4*)(attn_w + (size_t)bx * W4S + DD + t * 4);
        *(uint2*)(Bp + (size_t)bx * DD + t * 4) =
            make_uint2(pk2_rne(v.x, v.y), pk2_rne(v.z, v.w));
        return;
    }
    bx -= HH;                                       // base: one wave per (b,h)
    int wid  = bx * 4 + (threadIdx.x >> 6);
    int lane = threadIdx.x & 63;
    int b = wid >> 9;
    int h = wid & (HH - 1);
    const float4* h4 = (const float4*)(hidden + (size_t)(LL - 1) * BB * DD + (size_t)b * DD);
    const float4* w4 = (const float4*)(attn_w + (size_t)h * W4S);
    float s = 0.f;
    #pragma unroll
    for (int i = 0; i < 4; i++) {
        float4 a = h4[lane + i * 64], w = w4[lane + i * 64];
        s += a.x * w.x + a.y * w.y + a.z * w.z + a.w * w.w;
    }
    #pragma unroll
    for (int off = 32; off; off >>= 1) s += __shfl_xor(s, off);
    if (lane == 0) base[b * HH + h] = s + attn_b[h];
}

// ---------------- big GEMM: fragment-major LDS, 1 barrier/k-tile -------------
// C[m,n] = sum_k enc[m,k]*w_e[n,k]; scores[m] += sum_n tanh(C+base)*v
// LDS layout: fragment (mi,s) of A at As[buf][((mi*2+s)*64+lane)*8] (16 B/lane,
// lane-contiguous -> conflict-free b128 r/w). B same, per wave, filled by
// global_load_lds (dest = uniform base + lane*16 by construction).
__global__ __launch_bounds__(256, 2) void k_scores(const float* __restrict__ enc,
                                                   const unsigned short* __restrict__ Bp,
                                                   const float* __restrict__ base,
                                                   const float* __restrict__ vw,
                                                   float* __restrict__ scores) {
    __shared__ short As[2][8 * 64 * 8];        // 2 x 8 KB
    __shared__ short Bs[2][4][8 * 64 * 8];     // 2 x 4 x 8 KB

    const int tid  = threadIdx.x;
    const int wid  = tid >> 6;
    const int lane = tid & 63;
    const int lm   = lane & 15;
    const int kq   = lane >> 4;
    const int n0   = blockIdx.x * BN;          // 0 or 256
    const int m0   = blockIdx.y * BM;
    const int b    = m0 >> 11;
    const int wn   = n0 + wid * 64;

    // A staging: this thread owns fragment (mi=wid, s=0/1, lane):
    //   A[m0 + wid*16 + lm][kt*64 + s*32 + kq*8 .. +8]
    const float* Ag = enc + (size_t)(m0 + wid * 16 + lm) * DD + kq * 8;
    // B staging source (per-lane scatter): row wn+ni*16+lm, col kt*64+s*32+kq*8
    const unsigned short* Bgl = Bp + (size_t)(wn + lm) * DD + kq * 8;

    // ---- prologue: B(0) in flight, A(0) packed to LDS, A(1) in regs ----
    #pragma unroll
    for (int ni = 0; ni < 4; ni++)
        #pragma unroll
        for (int s = 0; s < 2; s++)
            gl_lds16(Bgl + (size_t)ni * 16 * DD + s * 32,
                     &Bs[0][wid][(ni * 2 + s) * 64 * 8]);

    float4 ra[2][4];
    #pragma unroll
    for (int s = 0; s < 2; s++) {
        ra[0][s * 2 + 0] = *(const float4*)(Ag + s * 32);
        ra[0][s * 2 + 1] = *(const float4*)(Ag + s * 32 + 4);
        ra[1][s * 2 + 0] = *(const float4*)(Ag + 64 + s * 32);
        ra[1][s * 2 + 1] = *(const float4*)(Ag + 64 + s * 32 + 4);
    }
    #pragma unroll
    for (int s = 0; s < 2; s++) {
        float4 x = ra[0][s * 2], y = ra[0][s * 2 + 1];
        uint4 p = {pk2_hu(x.x, x.y), pk2_hu(x.z, x.w),
                   pk2_hu(y.x, y.y), pk2_hu(y.z, y.w)};
        *(uint4*)&As[0][((wid * 2 + s) * 64 + lane) * 8] = p;
    }

    f32x4 acc[4][4];
    #pragma unroll
    for (int i = 0; i < 4; i++)
        #pragma unroll
        for (int j = 0; j < 4; j++) acc[i][j] = (f32x4){0.f, 0.f, 0.f, 0.f};

    #pragma unroll 2
    for (int kt = 0; kt < NT; kt++) {
        const int c = kt & 1;
        __syncthreads();   // buf c now fully valid for everyone
        if (kt + 1 < NT) {
            // B(kt+1) -> other buffer (read window for it is kt+1)
            #pragma unroll
            for (int ni = 0; ni < 4; ni++)
                #pragma unroll
                for (int s = 0; s < 2; s++)
                    gl_lds16(Bgl + (size_t)ni * 16 * DD + (kt + 1) * 64 + s * 32,
                             &Bs[c ^ 1][wid][(ni * 2 + s) * 64 * 8]);
            // A(kt+2) raw loads (consumed next iteration)
            if (kt + 2 < NT) {
                #pragma unroll
                for (int s = 0; s < 2; s++) {
                    ra[c][s * 2 + 0] = *(const float4*)(Ag + (kt + 2) * 64 + s * 32);
                    ra[c][s * 2 + 1] = *(const float4*)(Ag + (kt + 2) * 64 + s * 32 + 4);
                }
            }
            // pack A(kt+1) (regs loaded a full iteration ago) -> other buffer
            #pragma unroll
            for (int s = 0; s < 2; s++) {
                float4 x = ra[c ^ 1][s * 2], y = ra[c ^ 1][s * 2 + 1];
                uint4 p = {pk2_hu(x.x, x.y), pk2_hu(x.z, x.w),
                           pk2_hu(y.x, y.y), pk2_hu(y.z, y.w)};
                *(uint4*)&As[c ^ 1][((wid * 2 + s) * 64 + lane) * 8] = p;
            }
        }
        // MFMA on buffer c — all LDS reads lane-contiguous (conflict-free)
        #pragma unroll
        for (int s = 0; s < 2; s++) {
            bf16x8 af[4];
            #pragma unroll
            for (int mi = 0; mi < 4; mi++)
                af[mi] = *(const bf16x8*)&As[c][((mi * 2 + s) * 64 + lane) * 8];
            #pragma unroll
            for (int ni = 0; ni < 4; ni++) {
                bf16x8 bf = *(const bf16x8*)&Bs[c][wid][((ni * 2 + s) * 64 + lane) * 8];
                #pragma unroll
                for (int mi = 0; mi < 4; mi++)
                    acc[mi][ni] = __builtin_amdgcn_mfma_f32_16x16x32_bf16(
                        af[mi], bf, acc[mi][ni], 0, 0, 0);
            }
        }
    }

    // epilogue: p[mi][r] = sum over wave's 64 cols of tanh(C+base)*v
    const float* basep = base + b * HH + wn;
    const float* vp    = vw + wn;
    float p[4][4] = {};
    #pragma unroll
    for (int ni = 0; ni < 4; ni++) {
        int nl = ni * 16 + lm;
        float bs = basep[nl];
        float vv = vp[nl];
        #pragma unroll
        for (int mi = 0; mi < 4; mi++)
            #pragma unroll
            for (int r = 0; r < 4; r++)
                p[mi][r] += vv * fast_tanh(acc[mi][ni][r] + bs);
    }
    #pragma unroll
    for (int off = 8; off; off >>= 1)
        #pragma unroll
        for (int mi = 0; mi < 4; mi++)
            #pragma unroll
            for (int r = 0; r < 4; r++)
                p[mi][r] += __shfl_xor(p[mi][r], off);
    if (lm == 0) {
        #pragma unroll
        for (int mi = 0; mi < 4; mi++)
            #pragma unroll
            for (int r = 0; r < 4; r++)
                atomicAdd(&scores[m0 + mi * 16 + kq * 4 + r], p[mi][r]);
    }
}

// ---------------- softmax stats per batch: m, 1/sum --------------------------
__global__ __launch_bounds__(256) void k_smstat(const float* __restrict__ scores,
                                                float2* __restrict__ stat) {
    int b = blockIdx.x, tid = threadIdx.x;
    const float* rowp = scores + b * SS;
    float v[8];
    float m = -1e30f;
    #pragma unroll
    for (int i = 0; i < 8; i++) { v[i] = rowp[tid + i * 256]; m = fmaxf(m, v[i]); }
    __shared__ float sm[4], ssum[4];
    #pragma unroll
    for (int off = 32; off; off >>= 1) m = fmaxf(m, __shfl_xor(m, off));
    if ((tid & 63) == 0) sm[tid >> 6] = m;
    __syncthreads();
    m = fmaxf(fmaxf(sm[0], sm[1]), fmaxf(sm[2], sm[3]));
    float s = 0.f;
    #pragma unroll
    for (int i = 0; i < 8; i++) s += __expf(v[i] - m);
    #pragma unroll
    for (int off = 32; off; off >>= 1) s += __shfl_xor(s, off);
    if ((tid & 63) == 0) ssum[tid >> 6] = s;
    __syncthreads();
    if (tid == 0) {
        float tot = ssum[0] + ssum[1] + ssum[2] + ssum[3];
        stat[b] = make_float2(m, 1.f / tot);
    }
}

// ---------------- context partials + attention-weight write ------------------
#define CCH 64
__global__ __launch_bounds__(256) void k_ctxpart(const float* __restrict__ enc,
                                                 const float* __restrict__ scores,
                                                 const float2* __restrict__ stat,
                                                 float* __restrict__ attn_out,
                                                 float* __restrict__ part) {
    int b = blockIdx.x, c = blockIdx.y, tid = threadIdx.x;
    __shared__ float wsh[CCH];
    float2 st = stat[b];
    if (tid < CCH) {
        float w = __expf(scores[b * SS + c * CCH + tid] - st.x) * st.y;
        wsh[tid] = w;
        attn_out[b * SS + c * CCH + tid] = w;
    }
    __syncthreads();
    const float4* e4 = (const float4*)(enc + ((size_t)b * SS + c * CCH) * DD);
    float4 acc = {0.f, 0.f, 0.f, 0.f};
    #pragma unroll 8
    for (int s = 0; s < CCH; s++) {
        float wv  = wsh[s];
        float4 ev = e4[(size_t)s * (DD / 4) + tid];
        acc.x += wv * ev.x; acc.y += wv * ev.y;
        acc.z += wv * ev.z; acc.w += wv * ev.w;
    }
    *(float4*)(part + (size_t)(b * 32 + c) * DD + tid * 4) = acc;
}

__global__ __launch_bounds__(256) void k_ctxreduce(const float* __restrict__ part,
                                                   float* __restrict__ ctx) {
    int b = blockIdx.x, d = blockIdx.y * 256 + threadIdx.x;
    float s = 0.f;
    #pragma unroll
    for (int c = 0; c < 32; c++) s += part[(size_t)(b * 32 + c) * DD + d];
    ctx[b * DD + d] = s;
}

extern "C" void kernel_launch(void* const* d_in, const int* in_sizes, int n_in,
                              void* d_out, int out_size, void* d_ws, size_t ws_size,
                              hipStream_t stream) {
    const float* hidden = (const float*)d_in[0];   // (L,B,D)
    const float* enc    = (const float*)d_in[1];   // (B,S,D)
    const float* attn_w = (const float*)d_in[2];   // (H,4H)
    const float* attn_b = (const float*)d_in[3];   // (H,)
    const float* v_w    = (const float*)d_in[4];   // (1,H)

    float* out      = (float*)d_out;
    float* ctx_out  = out;               // (B,1,D)
    float* attn_out = out + BB * DD;     // (B,1,S)

    float* base        = (float*)d_ws;                          // B*H
    float* scores      = base + BB * HH;                        // B*S
    unsigned short* Bp = (unsigned short*)(scores + BB * SS);   // H*D bf16 (1 MB)
    float2* stat       = (float2*)(Bp + (size_t)HH * DD);       // B float2
    float* part        = (float*)(stat + BB);                   // 32*32*D (4 MB)

    hipLaunchKernelGGL(k_prep, dim3(BB * SS / 256 + HH + BB * HH / 4), dim3(256),
                       0, stream, hidden, attn_w, attn_b, Bp, base, scores);
    hipLaunchKernelGGL(k_scores, dim3(2, BB * SS / BM), dim3(256), 0, stream,
                       enc, Bp, base, v_w, scores);
    hipLaunchKernelGGL(k_smstat, dim3(BB), dim3(256), 0, stream, scores, stat);
    hipLaunchKernelGGL(k_ctxpart, dim3(BB, SS / CCH), dim3(256), 0, stream,
                       enc, scores, stat, attn_out, part);
    hipLaunchKernelGGL(k_ctxreduce, dim3(BB, DD / 256), dim3(256), 0, stream,
                       part, ctx_out);
}